// Round 13
// baseline (395.678 us; speedup 1.0000x reference)
//
#include <hip/hip_runtime.h>

#define LEAKY 0.2f

typedef unsigned short ushort_t;
typedef __attribute__((ext_vector_type(8))) short short8;
typedef __attribute__((ext_vector_type(4))) float f32x4;

__device__ __forceinline__ unsigned short f2bf(float f) {
  unsigned u = __float_as_uint(f);
  unsigned r = (u + 0x7fff + ((u >> 16) & 1)) >> 16;  // RNE
  return (unsigned short)r;
}
__device__ __forceinline__ float bf2f(unsigned short u) {
  return __uint_as_float(((unsigned)u) << 16);
}

// ---------------- prep: zero cnt + both W transposes (one dispatch) ----------------
__global__ __launch_bounds__(256) void prep_k(int* __restrict__ cnt,
                                              const float* __restrict__ W0,
                                              const float* __restrict__ W1,
                                              ushort_t* __restrict__ W0h,
                                              ushort_t* __restrict__ W1h, int N) {
  int i = blockIdx.x * 256 + threadIdx.x;
  if (i < N) cnt[i] = 0;
  if (i < 256 * 128) {
    int k = i % 128, c = i / 128;
    W0h[i] = f2bf(W0[(long)k * 256 + c]);
  }
  if (i < 256 * 256) {
    int k = i % 256, c = i / 256;
    W1h[i] = f2bf(W1[(long)k * 256 + c]);
  }
}

// ---------------- CSR build ----------------
// count + record slot (atomic return value) -> fill needs no atomics
__global__ void count_k(const int* __restrict__ dst, int* __restrict__ cnt,
                        int* __restrict__ slot, int E) {
  int base = (blockIdx.x * blockDim.x + threadIdx.x) * 8;
  if (base + 7 < E) {
    int4 d0 = *(const int4*)(dst + base);
    int4 d1 = *(const int4*)(dst + base + 4);
    int4 s0, s1;
    s0.x = atomicAdd(&cnt[d0.x], 1);
    s0.y = atomicAdd(&cnt[d0.y], 1);
    s0.z = atomicAdd(&cnt[d0.z], 1);
    s0.w = atomicAdd(&cnt[d0.w], 1);
    s1.x = atomicAdd(&cnt[d1.x], 1);
    s1.y = atomicAdd(&cnt[d1.y], 1);
    s1.z = atomicAdd(&cnt[d1.z], 1);
    s1.w = atomicAdd(&cnt[d1.w], 1);
    *(int4*)(slot + base) = s0;
    *(int4*)(slot + base + 4) = s1;
  } else {
    for (int i = base; i < E; ++i) slot[i] = atomicAdd(&cnt[dst[i]], 1);
  }
}

__global__ __launch_bounds__(1024) void scan1_k(const int* __restrict__ cnt,
                                                int* __restrict__ ptr,
                                                int* __restrict__ bsum, int N) {
  int t = threadIdx.x;
  int i = blockIdx.x * 1024 + t;
  int v = (i < N) ? cnt[i] : 0;
  int lane = t & 63, w = t >> 6;
  int x = v;
  #pragma unroll
  for (int off = 1; off < 64; off <<= 1) {
    int y = __shfl_up(x, off, 64);
    if (lane >= off) x += y;
  }
  __shared__ int wsum[16];
  if (lane == 63) wsum[w] = x;
  __syncthreads();
  if (t < 16) {
    int s = wsum[t];
    #pragma unroll
    for (int off = 1; off < 16; off <<= 1) {
      int y = __shfl_up(s, off, 16);
      if (t >= off) s += y;
    }
    wsum[t] = s;
  }
  __syncthreads();
  int woff = (w > 0) ? wsum[w - 1] : 0;
  int incl = x + woff;
  if (i < N) ptr[i] = incl - v;
  if (t == 1023) bsum[blockIdx.x] = incl;
}

// merged scan2+scan3
__global__ __launch_bounds__(1024) void scan23_k(int* __restrict__ ptr,
                                                 const int* __restrict__ bsum,
                                                 int nb, int N, int E) {
  __shared__ int sh[64];
  int t = threadIdx.x;
  if (t < 64) {
    int v = (t < nb) ? bsum[t] : 0;
    int x = v;
    #pragma unroll
    for (int off = 1; off < 64; off <<= 1) {
      int y = __shfl_up(x, off, 64);
      if (t >= off) x += y;
    }
    sh[t] = x - v;
  }
  __syncthreads();
  int i = blockIdx.x * 1024 + t;
  if (i < N) ptr[i] += sh[blockIdx.x];
  if (i == 0) ptr[N] = E;
}

// ---------------- MFMA GEMM 128x256 tile, BK=64 + fused el/er; optional fused fill ----------------
#define LDT 72  // 64 k + 8 pad (bf16 elems)
template <int AF32, int FILL>
__global__ __launch_bounds__(256) void gemmT_k(const void* __restrict__ Ag_,
                                               const ushort_t* __restrict__ Bh,
                                               const float* __restrict__ alv,
                                               const float* __restrict__ arv,
                                               ushort_t* __restrict__ C,
                                               float* __restrict__ el,
                                               float* __restrict__ er,
                                               int N, int K, int gemmBlocks,
                                               const int* __restrict__ dstv,
                                               const int* __restrict__ srcv,
                                               const int* __restrict__ slot,
                                               const int* __restrict__ ptrc,
                                               int* __restrict__ adj, int E) {
  __shared__ ushort_t smem[128 * LDT + 256 * LDT];
  if (FILL && blockIdx.x >= gemmBlocks) {
    int base = ((blockIdx.x - gemmBlocks) * 256 + threadIdx.x) * 4;
    if (base + 3 < E) {
      int4 d = *(const int4*)(dstv + base);
      int4 s = *(const int4*)(srcv + base);
      int4 q = *(const int4*)(slot + base);
      adj[ptrc[d.x] + q.x] = s.x;
      adj[ptrc[d.y] + q.y] = s.y;
      adj[ptrc[d.z] + q.z] = s.z;
      adj[ptrc[d.w] + q.w] = s.w;
    } else {
      for (int i = base; i < E; ++i) adj[ptrc[dstv[i]] + slot[i]] = srcv[i];
    }
    return;
  }
  ushort_t* As = smem;
  ushort_t* Bs = smem + 128 * LDT;
  int t = threadIdx.x;
  int w = t >> 6, l = t & 63;
  int wv_r = w >> 1, wv_c = w & 1;
  long row0 = (long)blockIdx.x * 128;
  int fr = l & 15;
  int ko = (l >> 4) * 8;
  int crow = (l >> 4) * 4;
  int ar = t >> 1;           // A row 0..127
  int ak = (t & 1) * 32;     // A k-offset 0 or 32
  int bc = t;                // B row 0..255
  f32x4 acc[4][8] = {};

  for (int k0 = 0; k0 < K; k0 += 64) {
    ushort4 ha[8];
    uint4 a0, a1, a2, a3;
    if (AF32) {
      const float* ap = (const float*)Ag_ + (row0 + ar) * (long)K + k0 + ak;
      #pragma unroll
      for (int q = 0; q < 8; ++q) {
        float4 v = *(const float4*)(ap + q * 4);
        ha[q] = make_ushort4(f2bf(v.x), f2bf(v.y), f2bf(v.z), f2bf(v.w));
      }
    } else {
      const ushort_t* ap = (const ushort_t*)Ag_ + (row0 + ar) * (long)K + k0 + ak;
      a0 = *(const uint4*)ap;
      a1 = *(const uint4*)(ap + 8);
      a2 = *(const uint4*)(ap + 16);
      a3 = *(const uint4*)(ap + 24);
    }
    const ushort_t* bp = Bh + (long)bc * K + k0;
    uint4 bv[8];
    #pragma unroll
    for (int q = 0; q < 8; ++q) bv[q] = *(const uint4*)(bp + q * 8);
    __syncthreads();
    if (AF32) {
      #pragma unroll
      for (int q = 0; q < 8; ++q)
        *(ushort4*)&As[ar * LDT + ak + q * 4] = ha[q];
    } else {
      *(uint4*)&As[ar * LDT + ak] = a0;
      *(uint4*)&As[ar * LDT + ak + 8] = a1;
      *(uint4*)&As[ar * LDT + ak + 16] = a2;
      *(uint4*)&As[ar * LDT + ak + 24] = a3;
    }
    #pragma unroll
    for (int q = 0; q < 8; ++q) *(uint4*)&Bs[bc * LDT + q * 8] = bv[q];
    __syncthreads();
    #pragma unroll
    for (int kk = 0; kk < 64; kk += 32) {
      short8 fah[4];
      #pragma unroll
      for (int m = 0; m < 4; ++m)
        fah[m] = *(const short8*)&As[(wv_r * 64 + m * 16 + fr) * LDT + ko + kk];
      #pragma unroll
      for (int n = 0; n < 8; ++n) {
        short8 fb = *(const short8*)&Bs[(wv_c * 128 + n * 16 + fr) * LDT + ko + kk];
        #pragma unroll
        for (int m = 0; m < 4; ++m)
          acc[m][n] = __builtin_amdgcn_mfma_f32_16x16x32_bf16(fah[m], fb, acc[m][n], 0, 0, 0);
      }
    }
  }
  float ala[4], alb[4], ara[4], arb[4];
  #pragma unroll
  for (int hd = 0; hd < 4; ++hd) {
    int hbase = (wv_c * 4 + hd) * 32;
    ala[hd] = alv[hbase + fr];
    alb[hd] = alv[hbase + 16 + fr];
    ara[hd] = arv[hbase + fr];
    arb[hd] = arv[hbase + 16 + fr];
  }
  #pragma unroll
  for (int m = 0; m < 4; ++m) {
    #pragma unroll
    for (int r = 0; r < 4; ++r) {
      long row = row0 + wv_r * 64 + m * 16 + crow + r;
      #pragma unroll
      for (int n = 0; n < 8; ++n)
        C[row * 256 + wv_c * 128 + n * 16 + fr] = f2bf(acc[m][n][r]);
      #pragma unroll
      for (int hd = 0; hd < 4; ++hd) {
        float pel = acc[m][2 * hd][r] * ala[hd] + acc[m][2 * hd + 1][r] * alb[hd];
        float per = acc[m][2 * hd][r] * ara[hd] + acc[m][2 * hd + 1][r] * arb[hd];
        #pragma unroll
        for (int s = 1; s < 16; s <<= 1) {
          pel += __shfl_xor(pel, s);
          per += __shfl_xor(per, s);
        }
        if (fr == 0) {
          el[row * 8 + wv_c * 4 + hd] = pel;
          er[row * 8 + wv_c * 4 + hd] = per;
        }
      }
    }
  }
}

// ---------------- agg: bf16 gather, wave-per-node (measured-best form) ----------------
__global__ __launch_bounds__(256) void agg_k(const ushort_t* __restrict__ hb,
                                             const float* __restrict__ el,
                                             const float* __restrict__ er,
                                             const int* __restrict__ ptr,
                                             const int* __restrict__ adj,
                                             ushort_t* __restrict__ oh, int N) {
  int wid = threadIdx.x >> 6;
  int l = threadIdx.x & 63;
  int n = blockIdx.x * 4 + wid;
  if (n >= N) return;
  int beg = ptr[n];
  int deg = ptr[n + 1] - beg;
  long obase = (long)n * 256 + l * 4;
  float4 acc = make_float4(0.f, 0.f, 0.f, 0.f);
  if (deg > 0) {
    int hh = l & 7;
    int eo = l >> 3;
    int hg = l >> 3;
    float erv = er[(long)n * 8 + hh];
    if (deg <= 64) {
      int sid = (l < deg) ? adj[beg + l] : 0;
      int npass = (deg + 7) >> 3;
      float v[8];
      float m = -1e30f;
      #pragma unroll
      for (int p = 0; p < 8; ++p) {
        if (p < npass) {
          int e = p * 8 + eo;
          int s = __shfl(sid, e);
          float vv = -1e30f;
          if (e < deg) {
            vv = el[(long)s * 8 + hh] + erv;
            vv = vv > 0.f ? vv : LEAKY * vv;
          }
          v[p] = vv;
          m = fmaxf(m, vv);
        }
      }
      m = fmaxf(m, __shfl_xor(m, 8));
      m = fmaxf(m, __shfl_xor(m, 16));
      m = fmaxf(m, __shfl_xor(m, 32));
      float ssum = 0.f;
      #pragma unroll
      for (int p = 0; p < 8; ++p) {
        if (p < npass) {
          float ex = (p * 8 + eo < deg) ? __expf(v[p] - m) : 0.f;
          v[p] = ex;
          ssum += ex;
        }
      }
      ssum += __shfl_xor(ssum, 8);
      ssum += __shfl_xor(ssum, 16);
      ssum += __shfl_xor(ssum, 32);
      float inv = 1.0f / ssum;
      #pragma unroll
      for (int p = 0; p < 8; ++p) {
        if (p < npass) {
          v[p] *= inv;
          #pragma unroll
          for (int e2 = 0; e2 < 8; ++e2) {
            int e = p * 8 + e2;
            if (e < deg) {
              float a = __shfl(v[p], (e2 << 3) | hg);
              int s = __shfl(sid, e);
              const ushort4 hv = *(const ushort4*)(hb + (long)s * 256 + l * 4);
              acc.x += a * bf2f(hv.x);
              acc.y += a * bf2f(hv.y);
              acc.z += a * bf2f(hv.z);
              acc.w += a * bf2f(hv.w);
            }
          }
        }
      }
    } else {
      float m = -1e30f;
      for (int base = 0; base < deg; base += 8) {
        int e = base + eo;
        float vv = -1e30f;
        if (e < deg) {
          int s = adj[beg + e];
          vv = el[(long)s * 8 + hh] + erv;
          vv = vv > 0.f ? vv : LEAKY * vv;
        }
        m = fmaxf(m, vv);
      }
      m = fmaxf(m, __shfl_xor(m, 8));
      m = fmaxf(m, __shfl_xor(m, 16));
      m = fmaxf(m, __shfl_xor(m, 32));
      float ssum = 0.f;
      for (int base = 0; base < deg; base += 8) {
        int e = base + eo;
        if (e < deg) {
          int s = adj[beg + e];
          float vv = el[(long)s * 8 + hh] + erv;
          vv = vv > 0.f ? vv : LEAKY * vv;
          ssum += __expf(vv - m);
        }
      }
      ssum += __shfl_xor(ssum, 8);
      ssum += __shfl_xor(ssum, 16);
      ssum += __shfl_xor(ssum, 32);
      float inv = 1.0f / ssum;
      for (int base = 0; base < deg; base += 8) {
        int e = base + eo;
        float a_me = 0.f;
        int s_me = 0;
        if (e < deg) {
          s_me = adj[beg + e];
          float vv = el[(long)s_me * 8 + hh] + erv;
          vv = vv > 0.f ? vv : LEAKY * vv;
          a_me = __expf(vv - m) * inv;
        }
        #pragma unroll
        for (int e2 = 0; e2 < 8; ++e2) {
          int e3 = base + e2;
          if (e3 < deg) {
            int srcl = (e2 << 3) | hg;
            float a = __shfl(a_me, srcl);
            int s = __shfl(s_me, srcl);
            const ushort4 hv = *(const ushort4*)(hb + (long)s * 256 + l * 4);
            acc.x += a * bf2f(hv.x);
            acc.y += a * bf2f(hv.y);
            acc.z += a * bf2f(hv.z);
            acc.w += a * bf2f(hv.w);
          }
        }
      }
    }
  }
  *(ushort4*)(oh + obase) =
      make_ushort4(f2bf(acc.x), f2bf(acc.y), f2bf(acc.z), f2bf(acc.w));
}

// ---------------- fused pool + MLP (bf16 h, 8-way unrolled pooling) ----------------
__device__ __forceinline__ int lower_bound_i(const int* a, int n, int key) {
  int lo = 0, hi = n;
  while (lo < hi) {
    int mid = (lo + hi) >> 1;
    if (a[mid] < key) lo = mid + 1; else hi = mid;
  }
  return lo;
}

__global__ __launch_bounds__(256) void poolmlp_k(const ushort_t* __restrict__ h,
                                                 const int* __restrict__ gid,
                                                 const float* __restrict__ Wd1,
                                                 const float* __restrict__ bd1,
                                                 const float* __restrict__ Wd2,
                                                 const float* __restrict__ bd2,
                                                 float* __restrict__ outv, int N, int G) {
  int g = blockIdx.x;
  int t = threadIdx.x;
  __shared__ int s_lo, s_hi;
  if (t == 0) {
    s_lo = lower_bound_i(gid, N, g);
    s_hi = lower_bound_i(gid, N, g + 1);
  }
  __syncthreads();
  int lo = s_lo, hi = s_hi;
  float a[8] = {};
  int n = lo;
  for (; n + 7 < hi; n += 8) {
    #pragma unroll
    for (int q = 0; q < 8; ++q) a[q] += bf2f(h[(long)(n + q) * 256 + t]);
  }
  for (; n < hi; ++n) a[0] += bf2f(h[(long)n * 256 + t]);
  float acc = ((a[0] + a[1]) + (a[2] + a[3])) + ((a[4] + a[5]) + (a[6] + a[7]));
  float c = (float)(hi - lo);
  __shared__ float p_s[256];
  __shared__ float red[256];
  p_s[t] = acc / fmaxf(c, 1.f);
  __syncthreads();
  float acc0 = bd1[t], acc1 = bd1[t + 256];
  for (int k = 0; k < 256; ++k) {
    float pv = p_s[k];
    acc0 += pv * Wd1[k * 512 + t];
    acc1 += pv * Wd1[k * 512 + t + 256];
  }
  acc0 = fmaxf(acc0, 0.f);
  acc1 = fmaxf(acc1, 0.f);
  red[t] = acc0 * Wd2[t] + acc1 * Wd2[t + 256];
  __syncthreads();
  for (int off = 128; off > 0; off >>= 1) {
    if (t < off) red[t] += red[t + off];
    __syncthreads();
  }
  if (t == 0) outv[g] = red[0] + bd2[0];
}

extern "C" void kernel_launch(void* const* d_in, const int* in_sizes, int n_in,
                              void* d_out, int out_size, void* d_ws, size_t ws_size,
                              hipStream_t stream) {
  const float* X   = (const float*)d_in[0];
  const int*   src = (const int*)d_in[1];
  const int*   dst = (const int*)d_in[2];
  const int*   gid = (const int*)d_in[3];
  const float* W0  = (const float*)d_in[5];
  const float* al0 = (const float*)d_in[6];
  const float* ar0 = (const float*)d_in[7];
  const float* W1  = (const float*)d_in[8];
  const float* al1 = (const float*)d_in[9];
  const float* ar1 = (const float*)d_in[10];
  const float* Wd1 = (const float*)d_in[11];
  const float* bd1 = (const float*)d_in[12];
  const float* Wd2 = (const float*)d_in[13];
  const float* bd2 = (const float*)d_in[14];

  int E = in_sizes[1];
  int N = in_sizes[3];
  int G = out_size;

  char* p = (char*)d_ws;
  ushort_t* hb   = (ushort_t*)p; p += (size_t)N * 256 * 2;   // GEMM C out (gathered)
  ushort_t* hagg = (ushort_t*)p; p += (size_t)N * 256 * 2;   // agg out (both layers)
  float*    el   = (float*)p;    p += (size_t)N * 8 * 4;
  float*    er   = (float*)p;    p += (size_t)N * 8 * 4;
  ushort_t* W0h  = (ushort_t*)p; p += (size_t)256 * 128 * 2;
  ushort_t* W1h  = (ushort_t*)p; p += (size_t)256 * 256 * 2;
  int*      ptr  = (int*)p;      p += (size_t)(N + 1) * 4;
  int*      cnt  = (int*)p;      p += (size_t)N * 4;
  int*      adj  = (int*)p;      p += (size_t)E * 4;
  int*      slot = (int*)p;      p += (size_t)E * 4;
  int*      bsum = (int*)p;

  int nb = (N + 1023) / 1024;
  int gemmBlocks = N / 128;
  int fillBlocks = (E / 4 + 255) / 256;

  // prep: zero cnt + W transposes
  prep_k<<<(N + 255) / 256, 256, 0, stream>>>(cnt, W0, W1, W0h, W1h, N);
  // CSR count + scans
  count_k<<<(E / 8 + 255) / 256, 256, 0, stream>>>(dst, cnt, slot, E);
  scan1_k<<<nb, 1024, 0, stream>>>(cnt, ptr, bsum, N);
  scan23_k<<<nb, 1024, 0, stream>>>(ptr, bsum, nb, N, E);

  // layer 0 GEMM with CSR fill fused in (independent work, one dispatch)
  gemmT_k<1, 1><<<gemmBlocks + fillBlocks, 256, 0, stream>>>(
      (const void*)X, W0h, al0, ar0, hb, el, er, N, 128, gemmBlocks,
      dst, src, slot, ptr, adj, E);
  agg_k<<<(N + 3) / 4, 256, 0, stream>>>(hb, el, er, ptr, adj, hagg, N);
  // layer 1
  gemmT_k<0, 0><<<gemmBlocks, 256, 0, stream>>>(
      (const void*)hagg, W1h, al1, ar1, hb, el, er, N, 256, gemmBlocks,
      nullptr, nullptr, nullptr, nullptr, nullptr, 0);
  agg_k<<<(N + 3) / 4, 256, 0, stream>>>(hb, el, er, ptr, adj, hagg, N);
  // readout + MLP
  poolmlp_k<<<G, 256, 0, stream>>>(hagg, gid, Wd1, bd1, Wd2, bd2, (float*)d_out, N, G);
}

// Round 14
// 379.689 us; speedup vs baseline: 1.0421x; 1.0421x over previous
//
#include <hip/hip_runtime.h>

#define LEAKY 0.2f

typedef unsigned short ushort_t;
typedef __attribute__((ext_vector_type(8))) short short8;
typedef __attribute__((ext_vector_type(4))) float f32x4;

__device__ __forceinline__ unsigned short f2bf(float f) {
  unsigned u = __float_as_uint(f);
  unsigned r = (u + 0x7fff + ((u >> 16) & 1)) >> 16;  // RNE
  return (unsigned short)r;
}
__device__ __forceinline__ float bf2f(unsigned short u) {
  return __uint_as_float(((unsigned)u) << 16);
}

// ---------------- prep: zero cnt + both W transposes (one dispatch) ----------------
__global__ __launch_bounds__(256) void prep_k(int* __restrict__ cnt,
                                              const float* __restrict__ W0,
                                              const float* __restrict__ W1,
                                              ushort_t* __restrict__ W0h,
                                              ushort_t* __restrict__ W1h, int N) {
  int i = blockIdx.x * 256 + threadIdx.x;
  if (i < N) cnt[i] = 0;
  if (i < 256 * 128) {
    int k = i % 128, c = i / 128;
    W0h[i] = f2bf(W0[(long)k * 256 + c]);
  }
  if (i < 256 * 256) {
    int k = i % 256, c = i / 256;
    W1h[i] = f2bf(W1[(long)k * 256 + c]);
  }
}

// ---------------- CSR build ----------------
// count + record slot (atomic return value) -> fill needs no atomics
__global__ void count_k(const int* __restrict__ dst, int* __restrict__ cnt,
                        int* __restrict__ slot, int E) {
  int base = (blockIdx.x * blockDim.x + threadIdx.x) * 8;
  if (base + 7 < E) {
    int4 d0 = *(const int4*)(dst + base);
    int4 d1 = *(const int4*)(dst + base + 4);
    int4 s0, s1;
    s0.x = atomicAdd(&cnt[d0.x], 1);
    s0.y = atomicAdd(&cnt[d0.y], 1);
    s0.z = atomicAdd(&cnt[d0.z], 1);
    s0.w = atomicAdd(&cnt[d0.w], 1);
    s1.x = atomicAdd(&cnt[d1.x], 1);
    s1.y = atomicAdd(&cnt[d1.y], 1);
    s1.z = atomicAdd(&cnt[d1.z], 1);
    s1.w = atomicAdd(&cnt[d1.w], 1);
    *(int4*)(slot + base) = s0;
    *(int4*)(slot + base + 4) = s1;
  } else {
    for (int i = base; i < E; ++i) slot[i] = atomicAdd(&cnt[dst[i]], 1);
  }
}

__global__ __launch_bounds__(1024) void scan1_k(const int* __restrict__ cnt,
                                                int* __restrict__ ptr,
                                                int* __restrict__ bsum, int N) {
  int t = threadIdx.x;
  int i = blockIdx.x * 1024 + t;
  int v = (i < N) ? cnt[i] : 0;
  int lane = t & 63, w = t >> 6;
  int x = v;
  #pragma unroll
  for (int off = 1; off < 64; off <<= 1) {
    int y = __shfl_up(x, off, 64);
    if (lane >= off) x += y;
  }
  __shared__ int wsum[16];
  if (lane == 63) wsum[w] = x;
  __syncthreads();
  if (t < 16) {
    int s = wsum[t];
    #pragma unroll
    for (int off = 1; off < 16; off <<= 1) {
      int y = __shfl_up(s, off, 16);
      if (t >= off) s += y;
    }
    wsum[t] = s;
  }
  __syncthreads();
  int woff = (w > 0) ? wsum[w - 1] : 0;
  int incl = x + woff;
  if (i < N) ptr[i] = incl - v;
  if (t == 1023) bsum[blockIdx.x] = incl;
}

// merged scan2+scan3
__global__ __launch_bounds__(1024) void scan23_k(int* __restrict__ ptr,
                                                 const int* __restrict__ bsum,
                                                 int nb, int N, int E) {
  __shared__ int sh[64];
  int t = threadIdx.x;
  if (t < 64) {
    int v = (t < nb) ? bsum[t] : 0;
    int x = v;
    #pragma unroll
    for (int off = 1; off < 64; off <<= 1) {
      int y = __shfl_up(x, off, 64);
      if (t >= off) x += y;
    }
    sh[t] = x - v;
  }
  __syncthreads();
  int i = blockIdx.x * 1024 + t;
  if (i < N) ptr[i] += sh[blockIdx.x];
  if (i == 0) ptr[N] = E;
}

// ---------------- MFMA GEMM 128x256 tile, BK=32 + fused el/er; optional fused fill ----------------
// Blocks < gemmBlocks: GEMM. Blocks >= gemmBlocks (FILL=1 only): atomic-free CSR fill.
#define LDT 40
template <int AF32, int FILL>
__global__ __launch_bounds__(256) void gemmT_k(const void* __restrict__ Ag_,
                                               const ushort_t* __restrict__ Bh,
                                               const float* __restrict__ alv,
                                               const float* __restrict__ arv,
                                               ushort_t* __restrict__ C,
                                               float* __restrict__ el,
                                               float* __restrict__ er,
                                               int N, int K, int gemmBlocks,
                                               const int* __restrict__ dstv,
                                               const int* __restrict__ srcv,
                                               const int* __restrict__ slot,
                                               const int* __restrict__ ptrc,
                                               int* __restrict__ adj, int E) {
  __shared__ ushort_t smem[128 * LDT + 256 * LDT];
  if (FILL && blockIdx.x >= gemmBlocks) {
    int base = ((blockIdx.x - gemmBlocks) * 256 + threadIdx.x) * 4;
    if (base + 3 < E) {
      int4 d = *(const int4*)(dstv + base);
      int4 s = *(const int4*)(srcv + base);
      int4 q = *(const int4*)(slot + base);
      adj[ptrc[d.x] + q.x] = s.x;
      adj[ptrc[d.y] + q.y] = s.y;
      adj[ptrc[d.z] + q.z] = s.z;
      adj[ptrc[d.w] + q.w] = s.w;
    } else {
      for (int i = base; i < E; ++i) adj[ptrc[dstv[i]] + slot[i]] = srcv[i];
    }
    return;
  }
  ushort_t* As = smem;
  ushort_t* Bs = smem + 128 * LDT;
  int t = threadIdx.x;
  int w = t >> 6, l = t & 63;
  int wv_r = w >> 1, wv_c = w & 1;
  long row0 = (long)blockIdx.x * 128;
  int fr = l & 15;
  int ko = (l >> 4) * 8;
  int crow = (l >> 4) * 4;
  int ar = t >> 1;
  int ak = (t & 1) * 16;
  int bc = t;
  f32x4 acc[4][8] = {};

  for (int k0 = 0; k0 < K; k0 += 32) {
    ushort4 ha[4];
    uint4 a0, a1;
    if (AF32) {
      const float* ap = (const float*)Ag_ + (row0 + ar) * (long)K + k0 + ak;
      float4 v0 = *(const float4*)(ap + 0);
      float4 v1 = *(const float4*)(ap + 4);
      float4 v2 = *(const float4*)(ap + 8);
      float4 v3 = *(const float4*)(ap + 12);
      ha[0] = make_ushort4(f2bf(v0.x), f2bf(v0.y), f2bf(v0.z), f2bf(v0.w));
      ha[1] = make_ushort4(f2bf(v1.x), f2bf(v1.y), f2bf(v1.z), f2bf(v1.w));
      ha[2] = make_ushort4(f2bf(v2.x), f2bf(v2.y), f2bf(v2.z), f2bf(v2.w));
      ha[3] = make_ushort4(f2bf(v3.x), f2bf(v3.y), f2bf(v3.z), f2bf(v3.w));
    } else {
      const ushort_t* ap = (const ushort_t*)Ag_ + (row0 + ar) * (long)K + k0 + ak;
      a0 = *(const uint4*)ap;
      a1 = *(const uint4*)(ap + 8);
    }
    const ushort_t* bp = Bh + (long)bc * K + k0;
    uint4 b0 = *(const uint4*)bp;
    uint4 b1 = *(const uint4*)(bp + 8);
    uint4 b2 = *(const uint4*)(bp + 16);
    uint4 b3 = *(const uint4*)(bp + 24);
    __syncthreads();
    if (AF32) {
      *(ushort4*)&As[ar * LDT + ak + 0] = ha[0];
      *(ushort4*)&As[ar * LDT + ak + 4] = ha[1];
      *(ushort4*)&As[ar * LDT + ak + 8] = ha[2];
      *(ushort4*)&As[ar * LDT + ak + 12] = ha[3];
    } else {
      *(uint4*)&As[ar * LDT + ak] = a0;
      *(uint4*)&As[ar * LDT + ak + 8] = a1;
    }
    *(uint4*)&Bs[bc * LDT + 0] = b0;
    *(uint4*)&Bs[bc * LDT + 8] = b1;
    *(uint4*)&Bs[bc * LDT + 16] = b2;
    *(uint4*)&Bs[bc * LDT + 24] = b3;
    __syncthreads();
    short8 fah[4];
    #pragma unroll
    for (int m = 0; m < 4; ++m)
      fah[m] = *(const short8*)&As[(wv_r * 64 + m * 16 + fr) * LDT + ko];
    #pragma unroll
    for (int n = 0; n < 8; ++n) {
      short8 fb = *(const short8*)&Bs[(wv_c * 128 + n * 16 + fr) * LDT + ko];
      #pragma unroll
      for (int m = 0; m < 4; ++m)
        acc[m][n] = __builtin_amdgcn_mfma_f32_16x16x32_bf16(fah[m], fb, acc[m][n], 0, 0, 0);
    }
  }
  float ala[4], alb[4], ara[4], arb[4];
  #pragma unroll
  for (int hd = 0; hd < 4; ++hd) {
    int hbase = (wv_c * 4 + hd) * 32;
    ala[hd] = alv[hbase + fr];
    alb[hd] = alv[hbase + 16 + fr];
    ara[hd] = arv[hbase + fr];
    arb[hd] = arv[hbase + 16 + fr];
  }
  #pragma unroll
  for (int m = 0; m < 4; ++m) {
    #pragma unroll
    for (int r = 0; r < 4; ++r) {
      long row = row0 + wv_r * 64 + m * 16 + crow + r;
      #pragma unroll
      for (int n = 0; n < 8; ++n)
        C[row * 256 + wv_c * 128 + n * 16 + fr] = f2bf(acc[m][n][r]);
      #pragma unroll
      for (int hd = 0; hd < 4; ++hd) {
        float pel = acc[m][2 * hd][r] * ala[hd] + acc[m][2 * hd + 1][r] * alb[hd];
        float per = acc[m][2 * hd][r] * ara[hd] + acc[m][2 * hd + 1][r] * arb[hd];
        #pragma unroll
        for (int s = 1; s < 16; s <<= 1) {
          pel += __shfl_xor(pel, s);
          per += __shfl_xor(per, s);
        }
        if (fr == 0) {
          el[row * 8 + wv_c * 4 + hd] = pel;
          er[row * 8 + wv_c * 4 + hd] = per;
        }
      }
    }
  }
}

// ---------------- agg: bf16 gather, wave-per-node (measured-best form) ----------------
__global__ __launch_bounds__(256) void agg_k(const ushort_t* __restrict__ hb,
                                             const float* __restrict__ el,
                                             const float* __restrict__ er,
                                             const int* __restrict__ ptr,
                                             const int* __restrict__ adj,
                                             ushort_t* __restrict__ oh, int N) {
  int wid = threadIdx.x >> 6;
  int l = threadIdx.x & 63;
  int n = blockIdx.x * 4 + wid;
  if (n >= N) return;
  int beg = ptr[n];
  int deg = ptr[n + 1] - beg;
  long obase = (long)n * 256 + l * 4;
  float4 acc = make_float4(0.f, 0.f, 0.f, 0.f);
  if (deg > 0) {
    int hh = l & 7;
    int eo = l >> 3;
    int hg = l >> 3;
    float erv = er[(long)n * 8 + hh];
    if (deg <= 64) {
      int sid = (l < deg) ? adj[beg + l] : 0;
      int npass = (deg + 7) >> 3;
      float v[8];
      float m = -1e30f;
      #pragma unroll
      for (int p = 0; p < 8; ++p) {
        if (p < npass) {
          int e = p * 8 + eo;
          int s = __shfl(sid, e);
          float vv = -1e30f;
          if (e < deg) {
            vv = el[(long)s * 8 + hh] + erv;
            vv = vv > 0.f ? vv : LEAKY * vv;
          }
          v[p] = vv;
          m = fmaxf(m, vv);
        }
      }
      m = fmaxf(m, __shfl_xor(m, 8));
      m = fmaxf(m, __shfl_xor(m, 16));
      m = fmaxf(m, __shfl_xor(m, 32));
      float ssum = 0.f;
      #pragma unroll
      for (int p = 0; p < 8; ++p) {
        if (p < npass) {
          float ex = (p * 8 + eo < deg) ? __expf(v[p] - m) : 0.f;
          v[p] = ex;
          ssum += ex;
        }
      }
      ssum += __shfl_xor(ssum, 8);
      ssum += __shfl_xor(ssum, 16);
      ssum += __shfl_xor(ssum, 32);
      float inv = 1.0f / ssum;
      #pragma unroll
      for (int p = 0; p < 8; ++p) {
        if (p < npass) {
          v[p] *= inv;
          #pragma unroll
          for (int e2 = 0; e2 < 8; ++e2) {
            int e = p * 8 + e2;
            if (e < deg) {
              float a = __shfl(v[p], (e2 << 3) | hg);
              int s = __shfl(sid, e);
              const ushort4 hv = *(const ushort4*)(hb + (long)s * 256 + l * 4);
              acc.x += a * bf2f(hv.x);
              acc.y += a * bf2f(hv.y);
              acc.z += a * bf2f(hv.z);
              acc.w += a * bf2f(hv.w);
            }
          }
        }
      }
    } else {
      float m = -1e30f;
      for (int base = 0; base < deg; base += 8) {
        int e = base + eo;
        float vv = -1e30f;
        if (e < deg) {
          int s = adj[beg + e];
          vv = el[(long)s * 8 + hh] + erv;
          vv = vv > 0.f ? vv : LEAKY * vv;
        }
        m = fmaxf(m, vv);
      }
      m = fmaxf(m, __shfl_xor(m, 8));
      m = fmaxf(m, __shfl_xor(m, 16));
      m = fmaxf(m, __shfl_xor(m, 32));
      float ssum = 0.f;
      for (int base = 0; base < deg; base += 8) {
        int e = base + eo;
        if (e < deg) {
          int s = adj[beg + e];
          float vv = el[(long)s * 8 + hh] + erv;
          vv = vv > 0.f ? vv : LEAKY * vv;
          ssum += __expf(vv - m);
        }
      }
      ssum += __shfl_xor(ssum, 8);
      ssum += __shfl_xor(ssum, 16);
      ssum += __shfl_xor(ssum, 32);
      float inv = 1.0f / ssum;
      for (int base = 0; base < deg; base += 8) {
        int e = base + eo;
        float a_me = 0.f;
        int s_me = 0;
        if (e < deg) {
          s_me = adj[beg + e];
          float vv = el[(long)s_me * 8 + hh] + erv;
          vv = vv > 0.f ? vv : LEAKY * vv;
          a_me = __expf(vv - m) * inv;
        }
        #pragma unroll
        for (int e2 = 0; e2 < 8; ++e2) {
          int e3 = base + e2;
          if (e3 < deg) {
            int srcl = (e2 << 3) | hg;
            float a = __shfl(a_me, srcl);
            int s = __shfl(s_me, srcl);
            const ushort4 hv = *(const ushort4*)(hb + (long)s * 256 + l * 4);
            acc.x += a * bf2f(hv.x);
            acc.y += a * bf2f(hv.y);
            acc.z += a * bf2f(hv.z);
            acc.w += a * bf2f(hv.w);
          }
        }
      }
    }
  }
  *(ushort4*)(oh + obase) =
      make_ushort4(f2bf(acc.x), f2bf(acc.y), f2bf(acc.z), f2bf(acc.w));
}

// ---------------- fused pool + MLP (bf16 h, 8-way unrolled pooling) ----------------
__device__ __forceinline__ int lower_bound_i(const int* a, int n, int key) {
  int lo = 0, hi = n;
  while (lo < hi) {
    int mid = (lo + hi) >> 1;
    if (a[mid] < key) lo = mid + 1; else hi = mid;
  }
  return lo;
}

__global__ __launch_bounds__(256) void poolmlp_k(const ushort_t* __restrict__ h,
                                                 const int* __restrict__ gid,
                                                 const float* __restrict__ Wd1,
                                                 const float* __restrict__ bd1,
                                                 const float* __restrict__ Wd2,
                                                 const float* __restrict__ bd2,
                                                 float* __restrict__ outv, int N, int G) {
  int g = blockIdx.x;
  int t = threadIdx.x;
  __shared__ int s_lo, s_hi;
  if (t == 0) {
    s_lo = lower_bound_i(gid, N, g);
    s_hi = lower_bound_i(gid, N, g + 1);
  }
  __syncthreads();
  int lo = s_lo, hi = s_hi;
  float a[8] = {};
  int n = lo;
  for (; n + 7 < hi; n += 8) {
    #pragma unroll
    for (int q = 0; q < 8; ++q) a[q] += bf2f(h[(long)(n + q) * 256 + t]);
  }
  for (; n < hi; ++n) a[0] += bf2f(h[(long)n * 256 + t]);
  float acc = ((a[0] + a[1]) + (a[2] + a[3])) + ((a[4] + a[5]) + (a[6] + a[7]));
  float c = (float)(hi - lo);
  __shared__ float p_s[256];
  __shared__ float red[256];
  p_s[t] = acc / fmaxf(c, 1.f);
  __syncthreads();
  float acc0 = bd1[t], acc1 = bd1[t + 256];
  for (int k = 0; k < 256; ++k) {
    float pv = p_s[k];
    acc0 += pv * Wd1[k * 512 + t];
    acc1 += pv * Wd1[k * 512 + t + 256];
  }
  acc0 = fmaxf(acc0, 0.f);
  acc1 = fmaxf(acc1, 0.f);
  red[t] = acc0 * Wd2[t] + acc1 * Wd2[t + 256];
  __syncthreads();
  for (int off = 128; off > 0; off >>= 1) {
    if (t < off) red[t] += red[t + off];
    __syncthreads();
  }
  if (t == 0) outv[g] = red[0] + bd2[0];
}

extern "C" void kernel_launch(void* const* d_in, const int* in_sizes, int n_in,
                              void* d_out, int out_size, void* d_ws, size_t ws_size,
                              hipStream_t stream) {
  const float* X   = (const float*)d_in[0];
  const int*   src = (const int*)d_in[1];
  const int*   dst = (const int*)d_in[2];
  const int*   gid = (const int*)d_in[3];
  const float* W0  = (const float*)d_in[5];
  const float* al0 = (const float*)d_in[6];
  const float* ar0 = (const float*)d_in[7];
  const float* W1  = (const float*)d_in[8];
  const float* al1 = (const float*)d_in[9];
  const float* ar1 = (const float*)d_in[10];
  const float* Wd1 = (const float*)d_in[11];
  const float* bd1 = (const float*)d_in[12];
  const float* Wd2 = (const float*)d_in[13];
  const float* bd2 = (const float*)d_in[14];

  int E = in_sizes[1];
  int N = in_sizes[3];
  int G = out_size;

  char* p = (char*)d_ws;
  ushort_t* hb   = (ushort_t*)p; p += (size_t)N * 256 * 2;   // GEMM C out (gathered)
  ushort_t* hagg = (ushort_t*)p; p += (size_t)N * 256 * 2;   // agg out (both layers)
  float*    el   = (float*)p;    p += (size_t)N * 8 * 4;
  float*    er   = (float*)p;    p += (size_t)N * 8 * 4;
  ushort_t* W0h  = (ushort_t*)p; p += (size_t)256 * 128 * 2;
  ushort_t* W1h  = (ushort_t*)p; p += (size_t)256 * 256 * 2;
  int*      ptr  = (int*)p;      p += (size_t)(N + 1) * 4;
  int*      cnt  = (int*)p;      p += (size_t)N * 4;
  int*      adj  = (int*)p;      p += (size_t)E * 4;
  int*      slot = (int*)p;      p += (size_t)E * 4;
  int*      bsum = (int*)p;

  int nb = (N + 1023) / 1024;
  int gemmBlocks = N / 128;
  int fillBlocks = (E / 4 + 255) / 256;

  // prep: zero cnt + W transposes
  prep_k<<<(N + 255) / 256, 256, 0, stream>>>(cnt, W0, W1, W0h, W1h, N);
  // CSR count + scans
  count_k<<<(E / 8 + 255) / 256, 256, 0, stream>>>(dst, cnt, slot, E);
  scan1_k<<<nb, 1024, 0, stream>>>(cnt, ptr, bsum, N);
  scan23_k<<<nb, 1024, 0, stream>>>(ptr, bsum, nb, N, E);

  // layer 0 GEMM with CSR fill fused in (independent work, one dispatch)
  gemmT_k<1, 1><<<gemmBlocks + fillBlocks, 256, 0, stream>>>(
      (const void*)X, W0h, al0, ar0, hb, el, er, N, 128, gemmBlocks,
      dst, src, slot, ptr, adj, E);
  agg_k<<<(N + 3) / 4, 256, 0, stream>>>(hb, el, er, ptr, adj, hagg, N);
  // layer 1
  gemmT_k<0, 0><<<gemmBlocks, 256, 0, stream>>>(
      (const void*)hagg, W1h, al1, ar1, hb, el, er, N, 256, gemmBlocks,
      nullptr, nullptr, nullptr, nullptr, nullptr, 0);
  agg_k<<<(N + 3) / 4, 256, 0, stream>>>(hb, el, er, ptr, adj, hagg, N);
  // readout + MLP
  poolmlp_k<<<G, 256, 0, stream>>>(hagg, gid, Wd1, bd1, Wd2, bd2, (float*)d_out, N, G);
}